// Round 12
// baseline (201.447 us; speedup 1.0000x reference)
//
#include <hip/hip_runtime.h>

typedef __bf16 bf16x8 __attribute__((ext_vector_type(8)));
typedef unsigned short u16x8 __attribute__((ext_vector_type(8)));
typedef u16x8 u16x8_a __attribute__((may_alias));
typedef unsigned short u16x4 __attribute__((ext_vector_type(4)));
typedef u16x4 u16x4_a __attribute__((may_alias));
typedef unsigned int u32x4 __attribute__((ext_vector_type(4)));
typedef u32x4 u32x4_a __attribute__((may_alias));
typedef float f32x4 __attribute__((ext_vector_type(4)));

#define LOG2E 1.4426950408889634f
#define NEGV  -10000.0f

__device__ __forceinline__ float bf2f(unsigned short u){
  union{unsigned int i; float f;} x; x.i = ((unsigned int)u)<<16; return x.f;
}
__device__ __forceinline__ unsigned short f2bf(float f){
  union{float f; unsigned int i;} x; x.f=f;
  unsigned int i = x.i;
  return (unsigned short)((i + 0x7FFFu + ((i>>16)&1u)) >> 16);
}
__device__ __forceinline__ bf16x8 ldb(const unsigned short* p){
  return __builtin_bit_cast(bf16x8, *(const u16x8_a*)p);
}

// ---------------- prep: z<6 -> weight transpose+cast; z==6 -> cast inputs to Ab ----------------
__global__ __launch_bounds__(256) void prep(
    const float* __restrict__ w0, const float* __restrict__ w1,
    const float* __restrict__ w2, const float* __restrict__ w3,
    const float* __restrict__ w4, const float* __restrict__ w5,
    const float* __restrict__ word, const float* __restrict__ ent,
    unsigned short* __restrict__ outT, unsigned short* __restrict__ Ab)
{
  int tx = threadIdx.x, ty = threadIdx.y;
  if (blockIdx.z == 6){
    int blk = blockIdx.y*24 + blockIdx.x;
    int gtid = blk*256 + ty*32 + tx;
    for (int idx = gtid; idx < 417792; idx += 147456){
      float4 v = (idx < 393216) ? ((const float4*)word)[idx]
                                : ((const float4*)ent)[idx - 393216];
      u16x4 r; r[0]=f2bf(v.x); r[1]=f2bf(v.y); r[2]=f2bf(v.z); r[3]=f2bf(v.w);
      *(u16x4_a*)(Ab + (size_t)idx*4) = r;
    }
    return;
  }
  const float* src;
  switch (blockIdx.z){
    case 0: src = w0; break; case 1: src = w1; break; case 2: src = w2; break;
    case 3: src = w3; break; case 4: src = w4; break; default: src = w5; break;
  }
  unsigned short* dst = outT + (size_t)blockIdx.z * 589824;
  __shared__ float tile[32][33];
  int x0 = blockIdx.x*32, y0 = blockIdx.y*32;
  #pragma unroll
  for (int i=0;i<32;i+=8) tile[ty+i][tx] = src[(size_t)(y0+ty+i)*768 + x0+tx];
  __syncthreads();
  #pragma unroll
  for (int i=0;i<32;i+=8) dst[(size_t)(x0+ty+i)*768 + y0+tx] = f2bf(tile[tx][ty+i]);
}

// ---------------- projection GEMM, 64x128 tiles; V writes transposed into VbT ----------------
__global__ __launch_bounds__(256) void gemm2(
    const unsigned short* __restrict__ Ab, const unsigned short* __restrict__ wT,
    const float* __restrict__ bK, const float* __restrict__ bV,
    const float* __restrict__ bQ, const float* __restrict__ bWE,
    const float* __restrict__ bEW, const float* __restrict__ bEE,
    unsigned short* __restrict__ oK, unsigned short* __restrict__ oVT,
    unsigned short* __restrict__ oQ, unsigned short* __restrict__ oWE,
    unsigned short* __restrict__ oEW, unsigned short* __restrict__ oEE)
{
  int mt = blockIdx.x, ntile = blockIdx.y;
  int g, m0, mo;
  if      (mt < 34){ g=0; mo=mt;      m0=mo*64; }
  else if (mt < 68){ g=1; mo=mt-34;   m0=mo*64; }
  else if (mt <100){ g=2; mo=mt-68;   m0=mo*64; }
  else if (mt <132){ g=3; mo=mt-100;  m0=mo*64; }
  else if (mt <134){ g=4; mo=mt-132;  m0=2048+mo*64; }
  else             { g=5; mo=mt-134;  m0=2048+mo*64; }
  const unsigned short* A = Ab + (size_t)m0*768;
  const unsigned short* B = wT + (size_t)g*589824;
  const float* bias; unsigned short* out;
  switch (g){
    case 0: bias=bK;  out=oK  + (size_t)m0*768;    break;
    case 1: bias=bV;  out=0;                        break;  // transposed epilogue
    case 2: bias=bQ;  out=oQ  + (size_t)m0*768;    break;
    case 3: bias=bWE; out=oWE + (size_t)m0*768;    break;
    case 4: bias=bEW; out=oEW + (size_t)(mo*64)*768; break;
    default:bias=bEE; out=oEE + (size_t)(mo*64)*768; break;
  }
  int n0 = ntile*128;

  __shared__ __align__(16) unsigned short a_s[64*32];
  __shared__ __align__(16) unsigned short b_s[128*32];

  int tid  = threadIdx.x;
  int w    = tid>>6, lane = tid&63, quad = lane>>4, lr = lane&15;
  int wm   = (w&1)*32, wn = (w>>1)*64;

  f32x4 acc[2][4];
  #pragma unroll
  for (int i=0;i<2;i++) for (int j=0;j<4;j++) for (int r=0;r<4;r++) acc[i][j][r]=0.f;

  int ar = tid>>2, ak = (tid&3)*8;
  int br = tid>>1, bk = (tid&1)*16;
  const unsigned short* Arow = A + (size_t)ar*768 + ak;
  const unsigned short* Brow = B + (size_t)(n0+br)*768 + bk;

  for (int k0=0; k0<768; k0+=32){
    u16x8 av  = *(const u16x8_a*)(Arow + k0);
    u16x8 bv0 = *(const u16x8_a*)(Brow + k0);
    u16x8 bv1 = *(const u16x8_a*)(Brow + k0 + 8);
    __syncthreads();
    *(u16x8_a*)(a_s + ar*32 + ak)      = av;
    *(u16x8_a*)(b_s + br*32 + bk)      = bv0;
    *(u16x8_a*)(b_s + br*32 + bk + 8)  = bv1;
    __syncthreads();
    bf16x8 af[2], bfr[4];
    #pragma unroll
    for (int i=0;i<2;i++) af[i]  = ldb(a_s + (wm+i*16+lr)*32 + quad*8);
    #pragma unroll
    for (int j=0;j<4;j++) bfr[j] = ldb(b_s + (wn+j*16+lr)*32 + quad*8);
    #pragma unroll
    for (int i=0;i<2;i++)
      #pragma unroll
      for (int j=0;j<4;j++)
        acc[i][j] = __builtin_amdgcn_mfma_f32_16x16x32_bf16(af[i], bfr[j], acc[i][j], 0,0,0);
  }
  if (g == 1){
    // V: write transposed -> VbT[dim][key], u16x4 = 4 consecutive keys
    #pragma unroll
    for (int j=0;j<4;j++){
      int col = n0 + wn + j*16 + lr;
      float bb = bias[col];
      #pragma unroll
      for (int i=0;i<2;i++){
        int key0 = m0 + wm + i*16 + quad*4;
        u16x4 pk;
        #pragma unroll
        for (int r=0;r<4;r++) pk[r] = f2bf(acc[i][j][r] + bb);
        *(u16x4_a*)(oVT + (size_t)col*2176 + key0) = pk;
      }
    }
  } else {
    #pragma unroll
    for (int j=0;j<4;j++){
      int col = n0 + wn + j*16 + lr;
      float bb = bias[col];
      #pragma unroll
      for (int i=0;i<2;i++){
        int rowb = wm + i*16 + quad*4;
        #pragma unroll
        for (int r=0;r<4;r++)
          out[(size_t)(rowb+r)*768 + col] = f2bf(acc[i][j][r] + bb);
      }
    }
  }
}

// ---------------- 64-key-tile flash attention: XCD swizzle + 4-way key split ----------------
// word ids 0..1535: xcd=id&7, 16 q-rows/block, all 4 waves split the key range.
// entity ids 1536..1631: 16 q-rows/block, 4-way split over all 2176 keys.
__global__ __launch_bounds__(256) void attn64s(
  const unsigned short* __restrict__ Kb,  const unsigned short* __restrict__ VbT,
  const unsigned short* __restrict__ Qw,  const unsigned short* __restrict__ Qwe,
  const unsigned short* __restrict__ Qew, const unsigned short* __restrict__ Qee,
  const float* __restrict__ am,
  float* __restrict__ outw, float* __restrict__ oute)
{
  int id = blockIdx.x;
  int tid = threadIdx.x, w = tid>>6, lane = tid&63, quad = lane>>4, lr = lane&15;
  bool isword = id < 1536;
  int h, qrb;
  const unsigned short *Qa, *Qb;
  float* outp;
  if (isword){
    int xcd = id & 7, pos = id >> 3;     // pos in [0,192)
    h = pos >> 4;                        // 0..11
    int lc = pos & 15;                   // 0..15
    qrb = (xcd*16 + lc) * 16;            // 16-query chunk, XCD-local 256-q span
    Qa = Qw; Qb = Qwe; outp = outw;
  } else {
    int eid = id - 1536;
    h = eid % 12;
    qrb = (eid / 12) * 16;
    Qa = Qew; Qb = Qee; outp = oute;
  }

  __shared__ __align__(16) unsigned int p32[4][16*36];  // per-wave packed P (stride 36 u32)
  __shared__ float mrg[2][64][24];                      // 2-buffer hierarchical merge

  const unsigned short* qr = Qa + (size_t)(qrb+lr)*768 + h*64 + quad*8;
  bf16x8 qa0 = ldb(qr), qa1 = ldb(qr + 32);
  qr = Qb + (size_t)(qrb+lr)*768 + h*64 + quad*8;
  bf16x8 qb0 = ldb(qr), qb1 = ldb(qr + 32);

  float m_r[4], l_r[4];
  f32x4 o[4];
  #pragma unroll
  for (int r=0;r<4;r++){ m_r[r] = -1e30f; l_r[r] = 0.f; }
  #pragma unroll
  for (int n2=0;n2<4;n2++) for (int r=0;r<4;r++) o[n2][r] = 0.f;

  int lo, nw;
  if (isword){
    lo = qrb - 256; if (lo < 0) lo = 0; lo &= ~63;
    int hi = qrb + 272; if (hi > 2048) hi = 2048; hi = (hi + 63) & ~63;
    nw = (hi - lo) >> 6;
  } else { lo = 0; nw = 32; }
  int nc = nw + 2;

  unsigned int* p32w = p32[w];

  for (int c = w; c < nc; c += 4){
    bool entp = c >= nw;
    int j0 = entp ? (2048 + (c-nw)*64) : (lo + c*64);

    bf16x8 kf[4][2], vf[4][2];
    const unsigned short* kp = Kb + (size_t)(j0+lr)*768 + h*64 + quad*8;
    #pragma unroll
    for (int t=0;t<4;t++){
      kf[t][0] = ldb(kp + (size_t)t*16*768);
      kf[t][1] = ldb(kp + (size_t)t*16*768 + 32);
    }
    const unsigned short* vp = VbT + (size_t)(h*64 + lr)*2176 + j0 + quad*8;
    #pragma unroll
    for (int n2=0;n2<4;n2++){
      vf[n2][0] = ldb(vp + (size_t)n2*16*2176);
      vf[n2][1] = ldb(vp + (size_t)n2*16*2176 + 32);
    }

    bf16x8 qf0 = entp ? qb0 : qa0;
    bf16x8 qf1 = entp ? qb1 : qa1;
    f32x4 s[4];
    #pragma unroll
    for (int t=0;t<4;t++){
      f32x4 z = {0.f,0.f,0.f,0.f};
      z = __builtin_amdgcn_mfma_f32_16x16x32_bf16(qf0, kf[t][0], z, 0,0,0);
      z = __builtin_amdgcn_mfma_f32_16x16x32_bf16(qf1, kf[t][1], z, 0,0,0);
      s[t] = z;
    }

    float sc[4][4];
    bool wband = isword && !entp;
    #pragma unroll
    for (int t=0;t<4;t++){
      int j = j0 + t*16 + lr;
      float amj  = am[j];
      float addl = amj * LOG2E;
      #pragma unroll
      for (int r=0;r<4;r++){
        float sv = s[t][r];
        if (wband){
          sv += (amj != 0.f) ? NEGV : 0.f;                              // float_mask pre-add
          int i = qrb + quad*4 + r;
          bool ok = ((unsigned)(i - j + 256) <= 512u) && (sv != 0.f);   // band & !=0 quirk
          sv = ok ? sv : NEGV;
        }
        sc[t][r] = sv * (LOG2E*0.125f) + addl;
      }
    }

    #pragma unroll
    for (int r=0;r<4;r++){
      float mx = fmaxf(fmaxf(sc[0][r],sc[1][r]), fmaxf(sc[2][r],sc[3][r]));
      mx = fmaxf(mx, __shfl_xor(mx, 1));
      mx = fmaxf(mx, __shfl_xor(mx, 2));
      mx = fmaxf(mx, __shfl_xor(mx, 4));
      mx = fmaxf(mx, __shfl_xor(mx, 8));
      float mn = fmaxf(m_r[r], mx);
      float alpha = exp2f(m_r[r] - mn);
      m_r[r] = mn;
      float p0 = exp2f(sc[0][r]-mn), p1 = exp2f(sc[1][r]-mn);
      float p2 = exp2f(sc[2][r]-mn), p3 = exp2f(sc[3][r]-mn);
      unsigned short pb0 = f2bf(p0), pb1 = f2bf(p1);
      unsigned short pb2 = f2bf(p2), pb3 = f2bf(p3);
      float rs = (bf2f(pb0) + bf2f(pb1)) + (bf2f(pb2) + bf2f(pb3));
      rs += __shfl_xor(rs,1); rs += __shfl_xor(rs,2);
      rs += __shfl_xor(rs,4); rs += __shfl_xor(rs,8);
      l_r[r] = l_r[r]*alpha + rs;
      int row = quad*4 + r;
      p32w[row*36 + lr]      = (unsigned int)pb0 | ((unsigned int)pb1 << 16);
      p32w[row*36 + 16 + lr] = (unsigned int)pb2 | ((unsigned int)pb3 << 16);
      #pragma unroll
      for (int n2=0;n2<4;n2++) o[n2][r] *= alpha;
    }

    const unsigned int* pbp = &p32w[lr*36 + (quad&1)*8];
    u32x4 ra0 = *(const u32x4_a*)pbp;
    u32x4 rb0 = *(const u32x4_a*)(pbp + 4);
    u32x4 ra1 = *(const u32x4_a*)(pbp + 16);
    u32x4 rb1 = *(const u32x4_a*)(pbp + 20);
    unsigned int f0[4], f1[4];
    if (quad < 2){
      f0[0]=(ra0[0]&0xFFFFu)|(ra0[1]<<16); f0[1]=(ra0[2]&0xFFFFu)|(ra0[3]<<16);
      f0[2]=(rb0[0]&0xFFFFu)|(rb0[1]<<16); f0[3]=(rb0[2]&0xFFFFu)|(rb0[3]<<16);
      f1[0]=(ra1[0]&0xFFFFu)|(ra1[1]<<16); f1[1]=(ra1[2]&0xFFFFu)|(ra1[3]<<16);
      f1[2]=(rb1[0]&0xFFFFu)|(rb1[1]<<16); f1[3]=(rb1[2]&0xFFFFu)|(rb1[3]<<16);
    } else {
      f0[0]=(ra0[0]>>16)|(ra0[1]&0xFFFF0000u); f0[1]=(ra0[2]>>16)|(ra0[3]&0xFFFF0000u);
      f0[2]=(rb0[0]>>16)|(rb0[1]&0xFFFF0000u); f0[3]=(rb0[2]>>16)|(rb0[3]&0xFFFF0000u);
      f1[0]=(ra1[0]>>16)|(ra1[1]&0xFFFF0000u); f1[1]=(ra1[2]>>16)|(ra1[3]&0xFFFF0000u);
      f1[2]=(rb1[0]>>16)|(rb1[1]&0xFFFF0000u); f1[3]=(rb1[2]>>16)|(rb1[3]&0xFFFF0000u);
    }
    u32x4 v0v = {f0[0],f0[1],f0[2],f0[3]};
    u32x4 v1v = {f1[0],f1[1],f1[2],f1[3]};
    bf16x8 pf0 = __builtin_bit_cast(bf16x8, v0v);
    bf16x8 pf1 = __builtin_bit_cast(bf16x8, v1v);

    #pragma unroll
    for (int n2=0;n2<4;n2++){
      o[n2] = __builtin_amdgcn_mfma_f32_16x16x32_bf16(pf0, vf[n2][0], o[n2], 0,0,0);
      o[n2] = __builtin_amdgcn_mfma_f32_16x16x32_bf16(pf1, vf[n2][1], o[n2], 0,0,0);
    }
  }

  // ---- hierarchical 4->2->1 merge, 2 LDS buffers ----
  // round 1: waves 1,3 publish; waves 0,2 fold.
  if (w == 1 || w == 3){
    float* my = &mrg[w>>1][lane][0];
    #pragma unroll
    for (int r=0;r<4;r++){ my[r] = m_r[r]; my[4+r] = l_r[r]; }
    #pragma unroll
    for (int n2=0;n2<4;n2++)
      #pragma unroll
      for (int r=0;r<4;r++) my[8+n2*4+r] = o[n2][r];
  }
  __syncthreads();
  if (w == 0 || w == 2){
    const float* pr = &mrg[w>>1][lane][0];
    #pragma unroll
    for (int r=0;r<4;r++){
      float m2 = pr[r], l2 = pr[4+r];
      float M  = fmaxf(m_r[r], m2);
      float e1 = exp2f(m_r[r]-M), e2 = exp2f(m2-M);
      m_r[r] = M;
      l_r[r] = l_r[r]*e1 + l2*e2;
      #pragma unroll
      for (int n2=0;n2<4;n2++)
        o[n2][r] = o[n2][r]*e1 + pr[8+n2*4+r]*e2;
    }
  }
  __syncthreads();
  // round 2: wave 2 publishes; wave 0 folds and writes.
  if (w == 2){
    float* my = &mrg[0][lane][0];
    #pragma unroll
    for (int r=0;r<4;r++){ my[r] = m_r[r]; my[4+r] = l_r[r]; }
    #pragma unroll
    for (int n2=0;n2<4;n2++)
      #pragma unroll
      for (int r=0;r<4;r++) my[8+n2*4+r] = o[n2][r];
  }
  __syncthreads();
  if (w == 0){
    const float* pr = &mrg[0][lane][0];
    #pragma unroll
    for (int r=0;r<4;r++){
      float m2 = pr[r], l2 = pr[4+r];
      float M  = fmaxf(m_r[r], m2);
      float e1 = exp2f(m_r[r]-M), e2 = exp2f(m2-M);
      m_r[r] = M;
      l_r[r] = l_r[r]*e1 + l2*e2;
      #pragma unroll
      for (int n2=0;n2<4;n2++)
        o[n2][r] = o[n2][r]*e1 + pr[8+n2*4+r]*e2;
    }
    #pragma unroll
    for (int n2=0;n2<4;n2++)
      #pragma unroll
      for (int r=0;r<4;r++){
        int row = qrb + quad*4 + r;
        outp[(size_t)row*768 + h*64 + n2*16 + lr] = o[n2][r] / l_r[r];
      }
  }
}

extern "C" void kernel_launch(void* const* d_in, const int* in_sizes, int n_in,
                              void* d_out, int out_size, void* d_ws, size_t ws_size,
                              hipStream_t stream) {
  const float* word  = (const float*)d_in[0];
  const float* ent   = (const float*)d_in[1];
  const float* am    = (const float*)d_in[2];
  const float* q_w   = (const float*)d_in[3];
  const float* q_b   = (const float*)d_in[4];
  const float* k_w   = (const float*)d_in[5];
  const float* k_b   = (const float*)d_in[6];
  const float* v_w   = (const float*)d_in[7];
  const float* v_b   = (const float*)d_in[8];
  const float* w2e_w = (const float*)d_in[9];
  const float* w2e_b = (const float*)d_in[10];
  const float* e2w_w = (const float*)d_in[11];
  const float* e2w_b = (const float*)d_in[12];
  const float* e2e_w = (const float*)d_in[13];
  const float* e2e_b = (const float*)d_in[14];

  unsigned short* ws  = (unsigned short*)d_ws;
  unsigned short* wT  = ws;                       // 6*768*768 bf16
  unsigned short* Ab  = wT  + (size_t)6*589824;   // 2176*768
  unsigned short* Kb  = Ab  + (size_t)2176*768;   // 2176*768
  unsigned short* VbT = Kb  + (size_t)2176*768;   // 768*2176 (V, transposed)
  unsigned short* Qw  = VbT + (size_t)768*2176;   // 2048*768
  unsigned short* Qwe = Qw  + (size_t)2048*768;
  unsigned short* Qew = Qwe + (size_t)2048*768;   // 128*768
  unsigned short* Qee = Qew + (size_t)128*768;

  float* outw = (float*)d_out;                    // fp32 output
  float* oute = outw + (size_t)2048*768;

  hipLaunchKernelGGL(prep, dim3(24,24,7), dim3(32,8), 0, stream,
                     k_w, v_w, q_w, w2e_w, e2w_w, e2e_w, word, ent, wT, Ab);
  hipLaunchKernelGGL(gemm2, dim3(136,6), dim3(256), 0, stream,
                     Ab, wT, k_b, v_b, q_b, w2e_b, e2w_b, e2e_b,
                     Kb, VbT, Qw, Qwe, Qew, Qee);
  hipLaunchKernelGGL(attn64s, dim3(1632), dim3(256), 0, stream,
                     Kb, VbT, Qw, Qwe, Qew, Qee, am, outw, oute);
}

// Round 13
// 190.899 us; speedup vs baseline: 1.0553x; 1.0553x over previous
//
#include <hip/hip_runtime.h>

typedef __bf16 bf16x8 __attribute__((ext_vector_type(8)));
typedef unsigned short u16x8 __attribute__((ext_vector_type(8)));
typedef u16x8 u16x8_a __attribute__((may_alias));
typedef unsigned short u16x4 __attribute__((ext_vector_type(4)));
typedef u16x4 u16x4_a __attribute__((may_alias));
typedef unsigned int u32x4 __attribute__((ext_vector_type(4)));
typedef u32x4 u32x4_a __attribute__((may_alias));
typedef float f32x4 __attribute__((ext_vector_type(4)));

#define LOG2E 1.4426950408889634f
#define NEGV  -10000.0f

__device__ __forceinline__ float bf2f(unsigned short u){
  union{unsigned int i; float f;} x; x.i = ((unsigned int)u)<<16; return x.f;
}
__device__ __forceinline__ unsigned short f2bf(float f){
  union{float f; unsigned int i;} x; x.f=f;
  unsigned int i = x.i;
  return (unsigned short)((i + 0x7FFFu + ((i>>16)&1u)) >> 16);
}
__device__ __forceinline__ bf16x8 ldb(const unsigned short* p){
  return __builtin_bit_cast(bf16x8, *(const u16x8_a*)p);
}

// ---------------- prep: z<6 -> weight transpose+cast; z==6 -> cast inputs to Ab ----------------
__global__ __launch_bounds__(256) void prep(
    const float* __restrict__ w0, const float* __restrict__ w1,
    const float* __restrict__ w2, const float* __restrict__ w3,
    const float* __restrict__ w4, const float* __restrict__ w5,
    const float* __restrict__ word, const float* __restrict__ ent,
    unsigned short* __restrict__ outT, unsigned short* __restrict__ Ab)
{
  int tx = threadIdx.x, ty = threadIdx.y;
  if (blockIdx.z == 6){
    int blk = blockIdx.y*24 + blockIdx.x;
    int gtid = blk*256 + ty*32 + tx;
    for (int idx = gtid; idx < 417792; idx += 147456){
      float4 v = (idx < 393216) ? ((const float4*)word)[idx]
                                : ((const float4*)ent)[idx - 393216];
      u16x4 r; r[0]=f2bf(v.x); r[1]=f2bf(v.y); r[2]=f2bf(v.z); r[3]=f2bf(v.w);
      *(u16x4_a*)(Ab + (size_t)idx*4) = r;
    }
    return;
  }
  const float* src;
  switch (blockIdx.z){
    case 0: src = w0; break; case 1: src = w1; break; case 2: src = w2; break;
    case 3: src = w3; break; case 4: src = w4; break; default: src = w5; break;
  }
  unsigned short* dst = outT + (size_t)blockIdx.z * 589824;
  __shared__ float tile[32][33];
  int x0 = blockIdx.x*32, y0 = blockIdx.y*32;
  #pragma unroll
  for (int i=0;i<32;i+=8) tile[ty+i][tx] = src[(size_t)(y0+ty+i)*768 + x0+tx];
  __syncthreads();
  #pragma unroll
  for (int i=0;i<32;i+=8) dst[(size_t)(x0+ty+i)*768 + y0+tx] = f2bf(tile[tx][ty+i]);
}

// ---------------- projection GEMM, 64x128 tiles; V writes transposed into VbT ----------------
__global__ __launch_bounds__(256) void gemm2(
    const unsigned short* __restrict__ Ab, const unsigned short* __restrict__ wT,
    const float* __restrict__ bK, const float* __restrict__ bV,
    const float* __restrict__ bQ, const float* __restrict__ bWE,
    const float* __restrict__ bEW, const float* __restrict__ bEE,
    unsigned short* __restrict__ oK, unsigned short* __restrict__ oVT,
    unsigned short* __restrict__ oQ, unsigned short* __restrict__ oWE,
    unsigned short* __restrict__ oEW, unsigned short* __restrict__ oEE)
{
  int mt = blockIdx.x, ntile = blockIdx.y;
  int g, m0, mo;
  if      (mt < 34){ g=0; mo=mt;      m0=mo*64; }
  else if (mt < 68){ g=1; mo=mt-34;   m0=mo*64; }
  else if (mt <100){ g=2; mo=mt-68;   m0=mo*64; }
  else if (mt <132){ g=3; mo=mt-100;  m0=mo*64; }
  else if (mt <134){ g=4; mo=mt-132;  m0=2048+mo*64; }
  else             { g=5; mo=mt-134;  m0=2048+mo*64; }
  const unsigned short* A = Ab + (size_t)m0*768;
  const unsigned short* B = wT + (size_t)g*589824;
  const float* bias; unsigned short* out;
  switch (g){
    case 0: bias=bK;  out=oK  + (size_t)m0*768;    break;
    case 1: bias=bV;  out=0;                        break;  // transposed epilogue
    case 2: bias=bQ;  out=oQ  + (size_t)m0*768;    break;
    case 3: bias=bWE; out=oWE + (size_t)m0*768;    break;
    case 4: bias=bEW; out=oEW + (size_t)(mo*64)*768; break;
    default:bias=bEE; out=oEE + (size_t)(mo*64)*768; break;
  }
  int n0 = ntile*128;

  __shared__ __align__(16) unsigned short a_s[64*32];
  __shared__ __align__(16) unsigned short b_s[128*32];

  int tid  = threadIdx.x;
  int w    = tid>>6, lane = tid&63, quad = lane>>4, lr = lane&15;
  int wm   = (w&1)*32, wn = (w>>1)*64;

  f32x4 acc[2][4];
  #pragma unroll
  for (int i=0;i<2;i++) for (int j=0;j<4;j++) for (int r=0;r<4;r++) acc[i][j][r]=0.f;

  int ar = tid>>2, ak = (tid&3)*8;
  int br = tid>>1, bk = (tid&1)*16;
  const unsigned short* Arow = A + (size_t)ar*768 + ak;
  const unsigned short* Brow = B + (size_t)(n0+br)*768 + bk;

  for (int k0=0; k0<768; k0+=32){
    u16x8 av  = *(const u16x8_a*)(Arow + k0);
    u16x8 bv0 = *(const u16x8_a*)(Brow + k0);
    u16x8 bv1 = *(const u16x8_a*)(Brow + k0 + 8);
    __syncthreads();
    *(u16x8_a*)(a_s + ar*32 + ak)      = av;
    *(u16x8_a*)(b_s + br*32 + bk)      = bv0;
    *(u16x8_a*)(b_s + br*32 + bk + 8)  = bv1;
    __syncthreads();
    bf16x8 af[2], bfr[4];
    #pragma unroll
    for (int i=0;i<2;i++) af[i]  = ldb(a_s + (wm+i*16+lr)*32 + quad*8);
    #pragma unroll
    for (int j=0;j<4;j++) bfr[j] = ldb(b_s + (wn+j*16+lr)*32 + quad*8);
    #pragma unroll
    for (int i=0;i<2;i++)
      #pragma unroll
      for (int j=0;j<4;j++)
        acc[i][j] = __builtin_amdgcn_mfma_f32_16x16x32_bf16(af[i], bfr[j], acc[i][j], 0,0,0);
  }
  if (g == 1){
    #pragma unroll
    for (int j=0;j<4;j++){
      int col = n0 + wn + j*16 + lr;
      float bb = bias[col];
      #pragma unroll
      for (int i=0;i<2;i++){
        int key0 = m0 + wm + i*16 + quad*4;
        u16x4 pk;
        #pragma unroll
        for (int r=0;r<4;r++) pk[r] = f2bf(acc[i][j][r] + bb);
        *(u16x4_a*)(oVT + (size_t)col*2176 + key0) = pk;
      }
    }
  } else {
    #pragma unroll
    for (int j=0;j<4;j++){
      int col = n0 + wn + j*16 + lr;
      float bb = bias[col];
      #pragma unroll
      for (int i=0;i<2;i++){
        int rowb = wm + i*16 + quad*4;
        #pragma unroll
        for (int r=0;r<4;r++)
          out[(size_t)(rowb+r)*768 + col] = f2bf(acc[i][j][r] + bb);
      }
    }
  }
}

// ---------------- fixed-max flash attention: no running max, l via ones-MFMA ----------------
// word ids 0..767: 32 q-rows/block, waves {0,1}/{2,3} own 16 rows each, 2-way key split.
// entity ids 768..863: 16 q-rows/block, 4-way key split. XCD swizzle on word ids.
__global__ __launch_bounds__(256) void attn_fm(
  const unsigned short* __restrict__ Kb,  const unsigned short* __restrict__ VbT,
  const unsigned short* __restrict__ Qw,  const unsigned short* __restrict__ Qwe,
  const unsigned short* __restrict__ Qew, const unsigned short* __restrict__ Qee,
  const float* __restrict__ am,
  float* __restrict__ outw, float* __restrict__ oute)
{
  int id = blockIdx.x;
  int tid = threadIdx.x, w = tid>>6, lane = tid&63, quad = lane>>4, lr = lane&15;
  bool isword = id < 768;
  int h, qrb, kh, nsplit;
  const unsigned short *Qa, *Qb;
  float* outp;
  if (isword){
    int xcd = id & 7, pos = id >> 3;   // pos 0..95
    h = pos >> 3;                      // 0..11
    int sub = pos & 7;
    int wq = xcd*8 + sub;              // q-chunk 0..63 (32 q each); xcd-local 256-q span
    qrb = wq*32 + (w>>1)*16;
    kh = w & 1; nsplit = 2;
    Qa = Qw; Qb = Qwe; outp = outw;
  } else {
    int eid = id - 768;
    h = eid % 12;
    qrb = (eid / 12) * 16;
    kh = w; nsplit = 4;
    Qa = Qew; Qb = Qee; outp = oute;
  }

  __shared__ __align__(16) unsigned int p32[4][16*36];  // per-wave packed P
  __shared__ float mrg[3][64][20];                      // merge: l(4)+o(16) per lane

  const unsigned short* qr = Qa + (size_t)(qrb+lr)*768 + h*64 + quad*8;
  bf16x8 qa0 = ldb(qr), qa1 = ldb(qr + 32);
  qr = Qb + (size_t)(qrb+lr)*768 + h*64 + quad*8;
  bf16x8 qb0 = ldb(qr), qb1 = ldb(qr + 32);

  // all-ones B-frag for row-sum MFMA
  u16x8 onesu;
  #pragma unroll
  for (int i=0;i<8;i++) onesu[i] = 0x3F80;
  bf16x8 ones = __builtin_bit_cast(bf16x8, onesu);

  f32x4 o[4], l_acc;
  #pragma unroll
  for (int n2=0;n2<4;n2++) for (int r=0;r<4;r++) o[n2][r] = 0.f;
  for (int r=0;r<4;r++) l_acc[r] = 0.f;

  int lo, nw;
  if (isword){
    lo = qrb - 256; if (lo < 0) lo = 0; lo &= ~63;
    int hi = qrb + 272; if (hi > 2048) hi = 2048; hi = (hi + 63) & ~63;
    nw = (hi - lo) >> 6;
  } else { lo = 0; nw = 32; }
  int nc = nw + 2;

  unsigned int* p32w = p32[w];

  for (int c = kh; c < nc; c += nsplit){
    bool entp = c >= nw;
    int j0 = entp ? (2048 + (c-nw)*64) : (lo + c*64);

    bf16x8 kf[4][2], vf[4][2];
    const unsigned short* kp = Kb + (size_t)(j0+lr)*768 + h*64 + quad*8;
    #pragma unroll
    for (int t=0;t<4;t++){
      kf[t][0] = ldb(kp + (size_t)t*16*768);
      kf[t][1] = ldb(kp + (size_t)t*16*768 + 32);
    }
    const unsigned short* vp = VbT + (size_t)(h*64 + lr)*2176 + j0 + quad*8;
    #pragma unroll
    for (int n2=0;n2<4;n2++){
      vf[n2][0] = ldb(vp + (size_t)n2*16*2176);
      vf[n2][1] = ldb(vp + (size_t)n2*16*2176 + 32);
    }

    bf16x8 qf0 = entp ? qb0 : qa0;
    bf16x8 qf1 = entp ? qb1 : qa1;
    f32x4 s[4];
    #pragma unroll
    for (int t=0;t<4;t++){
      f32x4 z = {0.f,0.f,0.f,0.f};
      z = __builtin_amdgcn_mfma_f32_16x16x32_bf16(qf0, kf[t][0], z, 0,0,0);
      z = __builtin_amdgcn_mfma_f32_16x16x32_bf16(qf1, kf[t][1], z, 0,0,0);
      s[t] = z;
    }

    bool wband = isword && !entp;
    // fixed-max softmax: p = exp2(sc) directly (logits are tiny; shift-invariant)
    #pragma unroll
    for (int t=0;t<4;t+=2){
      unsigned short pb[2][4][2];  // [pair][r][t-half]
      #pragma unroll
      for (int u=0;u<2;u++){
        int tt = t+u;
        int j = j0 + tt*16 + lr;
        float amj  = am[j];
        float addl = amj * LOG2E;
        #pragma unroll
        for (int r=0;r<4;r++){
          float sv = s[tt][r];
          if (wband){
            sv += (amj != 0.f) ? NEGV : 0.f;                            // float_mask pre-add
            int i = qrb + quad*4 + r;
            bool ok = ((unsigned)(i - j + 256) <= 512u) && (sv != 0.f); // band & !=0 quirk
            sv = ok ? sv : NEGV;
          }
          pb[u][r][0] = 0; // placeholder (filled below)
          float sc = sv * (LOG2E*0.125f) + addl;
          pb[u][r][0] = f2bf(exp2f(sc));
        }
      }
      #pragma unroll
      for (int r=0;r<4;r++){
        int row = quad*4 + r;
        p32w[row*36 + (t>>1)*16 + lr] =
          (unsigned int)pb[0][r][0] | ((unsigned int)pb[1][r][0] << 16);
      }
    }

    const unsigned int* pbp = &p32w[lr*36 + (quad&1)*8];
    u32x4 ra0 = *(const u32x4_a*)pbp;
    u32x4 rb0 = *(const u32x4_a*)(pbp + 4);
    u32x4 ra1 = *(const u32x4_a*)(pbp + 16);
    u32x4 rb1 = *(const u32x4_a*)(pbp + 20);
    unsigned int f0[4], f1[4];
    if (quad < 2){
      f0[0]=(ra0[0]&0xFFFFu)|(ra0[1]<<16); f0[1]=(ra0[2]&0xFFFFu)|(ra0[3]<<16);
      f0[2]=(rb0[0]&0xFFFFu)|(rb0[1]<<16); f0[3]=(rb0[2]&0xFFFFu)|(rb0[3]<<16);
      f1[0]=(ra1[0]&0xFFFFu)|(ra1[1]<<16); f1[1]=(ra1[2]&0xFFFFu)|(ra1[3]<<16);
      f1[2]=(rb1[0]&0xFFFFu)|(rb1[1]<<16); f1[3]=(rb1[2]&0xFFFFu)|(rb1[3]<<16);
    } else {
      f0[0]=(ra0[0]>>16)|(ra0[1]&0xFFFF0000u); f0[1]=(ra0[2]>>16)|(ra0[3]&0xFFFF0000u);
      f0[2]=(rb0[0]>>16)|(rb0[1]&0xFFFF0000u); f0[3]=(rb0[2]>>16)|(rb0[3]&0xFFFF0000u);
      f1[0]=(ra1[0]>>16)|(ra1[1]&0xFFFF0000u); f1[1]=(ra1[2]>>16)|(ra1[3]&0xFFFF0000u);
      f1[2]=(rb1[0]>>16)|(rb1[1]&0xFFFF0000u); f1[3]=(rb1[2]>>16)|(rb1[3]&0xFFFF0000u);
    }
    u32x4 v0v = {f0[0],f0[1],f0[2],f0[3]};
    u32x4 v1v = {f1[0],f1[1],f1[2],f1[3]};
    bf16x8 pf0 = __builtin_bit_cast(bf16x8, v0v);
    bf16x8 pf1 = __builtin_bit_cast(bf16x8, v1v);

    #pragma unroll
    for (int n2=0;n2<4;n2++){
      o[n2] = __builtin_amdgcn_mfma_f32_16x16x32_bf16(pf0, vf[n2][0], o[n2], 0,0,0);
      o[n2] = __builtin_amdgcn_mfma_f32_16x16x32_bf16(pf1, vf[n2][1], o[n2], 0,0,0);
    }
    // row-sum via ones-MFMA (replaces shuffle reduction)
    l_acc = __builtin_amdgcn_mfma_f32_16x16x32_bf16(pf0, ones, l_acc, 0,0,0);
    l_acc = __builtin_amdgcn_mfma_f32_16x16x32_bf16(pf1, ones, l_acc, 0,0,0);
  }

  // ---- merge: plain sums (fixed max) ----
  bool pub = isword ? (kh == 1) : (w > 0);
  int  buf = isword ? (w >> 1) : (w - 1);
  if (pub){
    float* my = &mrg[buf][lane][0];
    #pragma unroll
    for (int r=0;r<4;r++) my[r] = l_acc[r];
    #pragma unroll
    for (int n2=0;n2<4;n2++)
      #pragma unroll
      for (int r=0;r<4;r++) my[4+n2*4+r] = o[n2][r];
  }
  __syncthreads();
  if (!pub){
    int nfold = isword ? 1 : 3;
    for (int p=0; p<nfold; p++){
      const float* pr = &mrg[isword ? buf : p][lane][0];
      #pragma unroll
      for (int r=0;r<4;r++) l_acc[r] += pr[r];
      #pragma unroll
      for (int n2=0;n2<4;n2++)
        #pragma unroll
        for (int r=0;r<4;r++) o[n2][r] += pr[4+n2*4+r];
    }
    #pragma unroll
    for (int n2=0;n2<4;n2++)
      #pragma unroll
      for (int r=0;r<4;r++){
        int row = qrb + quad*4 + r;
        outp[(size_t)row*768 + h*64 + n2*16 + lr] = o[n2][r] / l_acc[r];
      }
  }
}

extern "C" void kernel_launch(void* const* d_in, const int* in_sizes, int n_in,
                              void* d_out, int out_size, void* d_ws, size_t ws_size,
                              hipStream_t stream) {
  const float* word  = (const float*)d_in[0];
  const float* ent   = (const float*)d_in[1];
  const float* am    = (const float*)d_in[2];
  const float* q_w   = (const float*)d_in[3];
  const float* q_b   = (const float*)d_in[4];
  const float* k_w   = (const float*)d_in[5];
  const float* k_b   = (const float*)d_in[6];
  const float* v_w   = (const float*)d_in[7];
  const float* v_b   = (const float*)d_in[8];
  const float* w2e_w = (const float*)d_in[9];
  const float* w2e_b = (const float*)d_in[10];
  const float* e2w_w = (const float*)d_in[11];
  const float* e2w_b = (const float*)d_in[12];
  const float* e2e_w = (const float*)d_in[13];
  const float* e2e_b = (const float*)d_in[14];

  unsigned short* ws  = (unsigned short*)d_ws;
  unsigned short* wT  = ws;                       // 6*768*768 bf16
  unsigned short* Ab  = wT  + (size_t)6*589824;   // 2176*768
  unsigned short* Kb  = Ab  + (size_t)2176*768;   // 2176*768
  unsigned short* VbT = Kb  + (size_t)2176*768;   // 768*2176 (V, transposed)
  unsigned short* Qw  = VbT + (size_t)768*2176;   // 2048*768
  unsigned short* Qwe = Qw  + (size_t)2048*768;
  unsigned short* Qew = Qwe + (size_t)2048*768;   // 128*768
  unsigned short* Qee = Qew + (size_t)128*768;

  float* outw = (float*)d_out;                    // fp32 output
  float* oute = outw + (size_t)2048*768;

  hipLaunchKernelGGL(prep, dim3(24,24,7), dim3(32,8), 0, stream,
                     k_w, v_w, q_w, w2e_w, e2w_w, e2e_w, word, ent, wT, Ab);
  hipLaunchKernelGGL(gemm2, dim3(136,6), dim3(256), 0, stream,
                     Ab, wT, k_b, v_b, q_b, w2e_b, e2w_b, e2e_b,
                     Kb, VbT, Qw, Qwe, Qew, Qee);
  hipLaunchKernelGGL(attn_fm, dim3(864), dim3(256), 0, stream,
                     Kb, VbT, Qw, Qwe, Qew, Qee, am, outw, oute);
}